// Round 6
// baseline (188.247 us; speedup 1.0000x reference)
//
#include <hip/hip_runtime.h>
#include <hip/hip_bf16.h>

#define NN 50000
#define NPAD 50048           // 64-row padded for MFMA grid
#define NE 800000
#define NF 128
#define HH 96
#define TF 10
#define Z1DIM (HH + TF)   // 106
#define ZK 128            // padded K for layer-1 MFMA (Wt1 row stride)
#define NCH 4             // column chunks for the gather
#define CW 24             // real cols per chunk: NCH*CW == HH
#define CWP 32            // padded row stride (64B cache line); cols 28-29 hold fp32 dinv
#define NBK 196           // dst buckets of 256 nodes
#define CAP 5120          // per-bucket temp capacity
#define EPB 2048          // edges per fillA job (391 blocks)
#define FILLA_B ((NE + EPB - 1) / EPB)   // 391

#define WBLK (NF * HH / 4 / 256)       // 12
#define W1BLK (HH * ZK / 4 / 256)      // 12
#define GEMM_JOBS (NPAD / 64)          // 782
#define ZTS 136                        // LDS z-tile row stride (ushorts): 128 + 8 pad

typedef __attribute__((ext_vector_type(8))) short short8;
typedef __attribute__((ext_vector_type(8))) unsigned short ushort8;
typedef __attribute__((ext_vector_type(4))) float f32x4;

__device__ __forceinline__ float bu2f(unsigned short u) {
    union { unsigned int i; float f; } c;
    c.i = ((unsigned int)u) << 16;
    return c.f;
}
__device__ __forceinline__ unsigned short f2bu(float f) {
    union { __hip_bfloat16 h; unsigned short u; } c;
    c.h = __float2bfloat16(f);
    return c.u;
}
__device__ __forceinline__ float u2f32(unsigned short lo, unsigned short hi) {
    union { unsigned int i; float f; } c;
    c.i = ((unsigned int)hi << 16) | lo;
    return c.f;
}

// ---- kernel 1: bcur[b] = b*CAP ----
__global__ void k_init(int* __restrict__ bcur) {
    int t = threadIdx.x;
    if (t < NBK) bcur[t] = t * CAP;
}

// ---- kernel 2: fused {edge binning} | {weight transpose} ----
__global__ __launch_bounds__(256) void k_pre(const int* __restrict__ ei,
                                             int* __restrict__ bcur,
                                             int* __restrict__ temp,
                                             const float* __restrict__ W,
                                             const float* __restrict__ W1,
                                             unsigned short* __restrict__ Wt,
                                             unsigned short* __restrict__ Wt1) {
    const int t = threadIdx.x;
    if (blockIdx.x < FILLA_B) {
        // ---- fillA: bin edges into 196 dst-range buckets ----
        __shared__ int hist[NBK], bas[NBK];
        for (int m = t; m < NBK; m += 256) hist[m] = 0;
        __syncthreads();
        const int e0 = blockIdx.x * EPB;
        const int ecap = min(e0 + EPB, NE);
        for (int e = e0 + t; e < ecap; e += 256) {
            int d = ei[NE + e];
            atomicAdd(&hist[d >> 8], 1);
        }
        __syncthreads();
        for (int m = t; m < NBK; m += 256) {
            int c = hist[m];
            bas[m] = c ? atomicAdd(&bcur[m], c) : 0;
            hist[m] = 0;   // reuse as run cursor
        }
        __syncthreads();
        for (int e = e0 + t; e < ecap; e += 256) {
            int d = ei[NE + e], s = ei[e];
            int b = d >> 8;
            int r = atomicAdd(&hist[b], 1);
            temp[bas[b] + r] = ((d & 255) << 16) | s;
        }
        return;
    }
    int b = blockIdx.x - FILLA_B;
    if (b < WBLK) {
        int e = (b * 256 + t) * 4;
        int n = e >> 7, k = e & 127;
        ushort4 v;
        v.x = f2bu(W[(k + 0) * HH + n]);
        v.y = f2bu(W[(k + 1) * HH + n]);
        v.z = f2bu(W[(k + 2) * HH + n]);
        v.w = f2bu(W[(k + 3) * HH + n]);
        *(ushort4*)(Wt + e) = v;
    } else {
        int e = ((b - WBLK) * 256 + t) * 4;
        int n = e >> 7, k = e & 127;     // n in [0,96), k in [0,128)
        ushort4 v;
        v.x = (k + 0 < Z1DIM) ? f2bu(W1[(k + 0) * HH + n]) : (unsigned short)0;
        v.y = (k + 1 < Z1DIM) ? f2bu(W1[(k + 1) * HH + n]) : (unsigned short)0;
        v.z = (k + 2 < Z1DIM) ? f2bu(W1[(k + 2) * HH + n]) : (unsigned short)0;
        v.w = (k + 3 < Z1DIM) ? f2bu(W1[(k + 3) * HH + n]) : (unsigned short)0;
        *(ushort4*)(Wt1 + e) = v;
    }
}

// ---- kernel 3: fused {fillB: off + dinv-in-pad + csr scatter} | {MFMA GEMM} ----
// fillB blocks [0,196): per-bucket histogram + scans -> off[i]; fp32 rsqrt(deg+1)
// into hp_c chunk-0 pad cols 28-29; scatter csr.
// GEMM blocks [196,978): h = bf16(x)·Wt UNSCALED + fused x·W2[96:224] row-dot.
__global__ __launch_bounds__(256) void k_gg(const int* __restrict__ temp,
                                            const int* __restrict__ bcur,
                                            unsigned short* __restrict__ csr,
                                            int* __restrict__ off,
                                            const float* __restrict__ x,
                                            const unsigned short* __restrict__ Wt,
                                            const float* __restrict__ W2,
                                            unsigned short* __restrict__ hp_c,
                                            float* __restrict__ xw2) {
    const int t = threadIdx.x;
    if (blockIdx.x < NBK) {
        __shared__ int ls[256], lc[256];
        const int b = blockIdx.x;
        // exclusive scan of all bucket sizes -> this bucket's global base g0
        int szt = (t < NBK) ? (bcur[t] - t * CAP) : 0;
        ls[t] = szt;
        __syncthreads();
#pragma unroll
        for (int d = 1; d < 256; d <<= 1) {
            int u = (t >= d) ? ls[t - d] : 0;
            __syncthreads();
            ls[t] += u;
            __syncthreads();
        }
        const int g0 = (b > 0) ? ls[b - 1] : 0;
        __syncthreads();
        ls[t] = 0;
        __syncthreads();
        const int seg0 = b * CAP;
        const int m = bcur[b] - seg0;
        for (int k = t; k < m; k += 256) atomicAdd(&ls[temp[seg0 + k] >> 16], 1);
        __syncthreads();
        const int myc = ls[t];
        lc[t] = myc;
        __syncthreads();
#pragma unroll
        for (int d = 1; d < 256; d <<= 1) {
            int u = (t >= d) ? lc[t - d] : 0;
            __syncthreads();
            lc[t] += u;
            __syncthreads();
        }
        const int myoff = g0 + lc[t] - myc;   // absolute exclusive
        __syncthreads();
        lc[t] = myoff;                        // absolute cursor
        const int i = b * 256 + t;
        if (i < NN) {
            off[i] = myoff;
            // dinv into chunk-0 pad only (k_am broadcasts from chunk 0)
            *(float*)(hp_c + (size_t)i * CWP + 28) = rsqrtf((float)myc + 1.f);
        } else if (i == NN) {
            off[NN] = NE;
        }
        __syncthreads();
        for (int k = t; k < m; k += 256) {
            int v = temp[seg0 + k];
            int r = atomicAdd(&lc[v >> 16], 1);
            csr[r] = (unsigned short)(v & 0xFFFF);
        }
        return;
    }
    // ---- gemm ----
    const int wave = t >> 6;
    const int lane = t & 63;
    const int quad = lane >> 4;
    const int l16 = lane & 15;
    const int Mbase = (blockIdx.x - NBK) * 64 + wave * 16;
    const int row = Mbase + l16;
    const bool valid = row < NN;

    const float* xr = x + (size_t)row * NF + quad * 8;
    const unsigned short* brow = Wt + (size_t)l16 * NF + quad * 8;

    f32x4 acc[6] = {};
    float xs = 0.f;
#pragma unroll
    for (int ks = 0; ks < 4; ++ks) {
        short8 a = {};
        if (valid) {
            float4 f0 = *(const float4*)(xr + ks * 32);
            float4 f1 = *(const float4*)(xr + ks * 32 + 4);
            const float4 w0 = *(const float4*)(W2 + HH + quad * 8 + ks * 32);
            const float4 w1 = *(const float4*)(W2 + HH + quad * 8 + ks * 32 + 4);
            xs = fmaf(f0.x, w0.x, xs); xs = fmaf(f0.y, w0.y, xs);
            xs = fmaf(f0.z, w0.z, xs); xs = fmaf(f0.w, w0.w, xs);
            xs = fmaf(f1.x, w1.x, xs); xs = fmaf(f1.y, w1.y, xs);
            xs = fmaf(f1.z, w1.z, xs); xs = fmaf(f1.w, w1.w, xs);
            a[0] = (short)f2bu(f0.x); a[1] = (short)f2bu(f0.y);
            a[2] = (short)f2bu(f0.z); a[3] = (short)f2bu(f0.w);
            a[4] = (short)f2bu(f1.x); a[5] = (short)f2bu(f1.y);
            a[6] = (short)f2bu(f1.z); a[7] = (short)f2bu(f1.w);
        }
#pragma unroll
        for (int nt = 0; nt < 6; ++nt) {
            short8 bfrag = *(const short8*)(brow + (size_t)nt * 16 * NF + ks * 32);
            acc[nt] = __builtin_amdgcn_mfma_f32_16x16x32_bf16(a, bfrag, acc[nt], 0, 0, 0);
        }
    }
    xs += __shfl_xor(xs, 16, 64);
    xs += __shfl_xor(xs, 32, 64);
    if (quad == 0 && valid) xw2[row] = xs;

    const int r0 = Mbase + quad * 4;
#pragma unroll
    for (int nt = 0; nt < 6; ++nt) {
        int n = nt * 16 + l16;
        int c = n / CW, jj = n - c * CW;
        unsigned short* dst = hp_c + (size_t)c * NN * CWP + jj;
#pragma unroll
        for (int k = 0; k < 4; ++k)
            if (r0 + k < NN) dst[(size_t)(r0 + k) * CWP] = f2bu(acc[nt][k]);
    }
}

// ---- kernel 4: FUSED gather-aggregate + MFMA layer-1 + layer-2 epilogue ----
// Block owns 64 output nodes. Phase A: 4 lanes/node; per edge the quad fetches
// the four 64B chunk rows of the src (16 x 16B lane-loads, fully-used lines);
// dinv[src] rides in chunk-0 pad cols 28-29 -> __shfl(lane|3) broadcast.
// Result rows -> LDS zt[64][136] (bf16, 8-col pad vs bank conflicts), temporal
// tail cols [96,128) written by the q==3 lane from tmp. Phase B: 4 waves MFMA
// zt x Wt1 + ReLU + W2-dot + xw2 + bias -> out. zb intermediate eliminated.
__global__ __launch_bounds__(256) void k_am(const unsigned short* __restrict__ hp_c,
                                            const int* __restrict__ off,
                                            const unsigned short* __restrict__ csr,
                                            const float* __restrict__ bg,
                                            const float* __restrict__ tmp,
                                            const unsigned short* __restrict__ Wt1,
                                            const float* __restrict__ b1,
                                            const float* __restrict__ W2,
                                            const float* __restrict__ b2,
                                            const float* __restrict__ xw2,
                                            float* __restrict__ out) {
    __shared__ unsigned short zt[64][ZTS];
    const int t = threadIdx.x;
    const int n = t >> 2;                       // 0..63: node slot
    const int q = t & 3;                        // 16B quarter of each 64B row
    const int i = blockIdx.x * 64 + n;
    const int lane = t & 63;
    const int srcl = lane | 3;                  // q3 lane of this node's quad

    if (i < NN) {
        const unsigned short* __restrict__ b0 = hp_c + q * 8;
        const unsigned short* __restrict__ b1c = hp_c + (size_t)1 * NN * CWP + q * 8;
        const unsigned short* __restrict__ b2c = hp_c + (size_t)2 * NN * CWP + q * 8;
        const unsigned short* __restrict__ b3c = hp_c + (size_t)3 * NN * CWP + q * 8;

        float ac[4][8];
        {   // self-loop term: dinv[i] * h[i]
            ushort8 s0 = *(const ushort8*)(b0 + (size_t)i * CWP);
            ushort8 s1 = *(const ushort8*)(b1c + (size_t)i * CWP);
            ushort8 s2 = *(const ushort8*)(b2c + (size_t)i * CWP);
            ushort8 s3 = *(const ushort8*)(b3c + (size_t)i * CWP);
            float dsl = __shfl(u2f32(s0[4], s0[5]), srcl, 64);
#pragma unroll
            for (int j = 0; j < 8; ++j) {
                ac[0][j] = dsl * bu2f(s0[j]);
                ac[1][j] = dsl * bu2f(s1[j]);
                ac[2][j] = dsl * bu2f(s2[j]);
                ac[3][j] = dsl * bu2f(s3[j]);
            }
        }
        int k = off[i];
        const int ke = off[i + 1];
        const float dv = rsqrtf((float)(ke - k) + 1.f);
        for (; k + 1 < ke; k += 2) {    // 2 edges x 4 chunk-lines in flight
            int sA = csr[k], sB = csr[k + 1];
            ushort8 vA0 = *(const ushort8*)(b0 + (size_t)sA * CWP);
            ushort8 vA1 = *(const ushort8*)(b1c + (size_t)sA * CWP);
            ushort8 vA2 = *(const ushort8*)(b2c + (size_t)sA * CWP);
            ushort8 vA3 = *(const ushort8*)(b3c + (size_t)sA * CWP);
            ushort8 vB0 = *(const ushort8*)(b0 + (size_t)sB * CWP);
            ushort8 vB1 = *(const ushort8*)(b1c + (size_t)sB * CWP);
            ushort8 vB2 = *(const ushort8*)(b2c + (size_t)sB * CWP);
            ushort8 vB3 = *(const ushort8*)(b3c + (size_t)sB * CWP);
            float dA = __shfl(u2f32(vA0[4], vA0[5]), srcl, 64);
            float dB = __shfl(u2f32(vB0[4], vB0[5]), srcl, 64);
#pragma unroll
            for (int j = 0; j < 8; ++j) {
                ac[0][j] = fmaf(dB, bu2f(vB0[j]), fmaf(dA, bu2f(vA0[j]), ac[0][j]));
                ac[1][j] = fmaf(dB, bu2f(vB1[j]), fmaf(dA, bu2f(vA1[j]), ac[1][j]));
                ac[2][j] = fmaf(dB, bu2f(vB2[j]), fmaf(dA, bu2f(vA2[j]), ac[2][j]));
                ac[3][j] = fmaf(dB, bu2f(vB3[j]), fmaf(dA, bu2f(vA3[j]), ac[3][j]));
            }
        }
        if (k < ke) {
            int sA = csr[k];
            ushort8 vA0 = *(const ushort8*)(b0 + (size_t)sA * CWP);
            ushort8 vA1 = *(const ushort8*)(b1c + (size_t)sA * CWP);
            ushort8 vA2 = *(const ushort8*)(b2c + (size_t)sA * CWP);
            ushort8 vA3 = *(const ushort8*)(b3c + (size_t)sA * CWP);
            float dA = __shfl(u2f32(vA0[4], vA0[5]), srcl, 64);
#pragma unroll
            for (int j = 0; j < 8; ++j) {
                ac[0][j] = fmaf(dA, bu2f(vA0[j]), ac[0][j]);
                ac[1][j] = fmaf(dA, bu2f(vA1[j]), ac[1][j]);
                ac[2][j] = fmaf(dA, bu2f(vA2[j]), ac[2][j]);
                ac[3][j] = fmaf(dA, bu2f(vA3[j]), ac[3][j]);
            }
        }
        if (q < 3) {
#pragma unroll
            for (int c = 0; c < 4; ++c) {
                const int j0 = c * CW + q * 8;
                ushort8 o;
#pragma unroll
                for (int j = 0; j < 8; ++j)
                    o[j] = f2bu(fmaxf(fmaf(dv, ac[c][j], bg[j0 + j]), 0.f));
                *(ushort8*)(&zt[n][j0]) = o;
            }
        } else {
            // temporal tail: cols [96,106) = bf16(tmp[i][:]), [106,136) zero
            const float* tp = tmp + (size_t)i * TF;
            ushort8 o0, z = {};
#pragma unroll
            for (int j = 0; j < 8; ++j) o0[j] = f2bu(tp[j]);
            ushort8 o1 = z;
            o1[0] = f2bu(tp[8]);
            o1[1] = f2bu(tp[9]);
            *(ushort8*)(&zt[n][96]) = o0;
            *(ushort8*)(&zt[n][104]) = o1;
            *(ushort8*)(&zt[n][112]) = z;
            *(ushort8*)(&zt[n][120]) = z;
            *(ushort8*)(&zt[n][128]) = z;
        }
    } else {
        // pad node: zero the whole row this quad owns
        if (q < 3) {
#pragma unroll
            for (int c = 0; c < 4; ++c) {
                ushort8 z = {};
                *(ushort8*)(&zt[n][c * CW + q * 8]) = z;
            }
        } else {
            ushort8 z = {};
            *(ushort8*)(&zt[n][96]) = z;
            *(ushort8*)(&zt[n][104]) = z;
            *(ushort8*)(&zt[n][112]) = z;
            *(ushort8*)(&zt[n][120]) = z;
            *(ushort8*)(&zt[n][128]) = z;
        }
    }
    __syncthreads();

    // ---- Phase B: MFMA layer-1 from LDS + fused layer-2 epilogue ----
    const int wave = t >> 6;
    const int quadB = lane >> 4;
    const int l16 = lane & 15;
    const int Mrow = wave * 16 + l16;           // row within block
    const int Mbase = blockIdx.x * 64 + wave * 16;

    const unsigned short* brow = Wt1 + (size_t)l16 * ZK + quadB * 8;

    f32x4 acc[6] = {};
#pragma unroll
    for (int ks = 0; ks < 4; ++ks) {
        short8 a = *(const short8*)(&zt[Mrow][quadB * 8 + ks * 32]);
#pragma unroll
        for (int nt = 0; nt < 6; ++nt) {
            short8 bfrag = *(const short8*)(brow + (size_t)nt * 16 * ZK + ks * 32);
            acc[nt] = __builtin_amdgcn_mfma_f32_16x16x32_bf16(a, bfrag, acc[nt], 0, 0, 0);
        }
    }
    float bb[6], wa[6];
#pragma unroll
    for (int nt = 0; nt < 6; ++nt) {
        int cc = nt * 16 + l16;
        bb[nt] = b1[cc];
        wa[nt] = W2[cc];
    }
    const float bias2 = b2[0];

#pragma unroll
    for (int reg = 0; reg < 4; ++reg) {
        const int r = Mbase + quadB * 4 + reg;
        float p = 0.f;
#pragma unroll
        for (int nt = 0; nt < 6; ++nt)
            p = fmaf(fmaxf(acc[nt][reg] + bb[nt], 0.f), wa[nt], p);
#pragma unroll
        for (int m = 1; m < 16; m <<= 1) p += __shfl_xor(p, m, 64);
        if (l16 == 0 && r < NN) out[r] = fmaxf(p + xw2[r] + bias2, 0.f);
    }
}

extern "C" void kernel_launch(void* const* d_in, const int* in_sizes, int n_in,
                              void* d_out, int out_size, void* d_ws, size_t ws_size,
                              hipStream_t stream) {
    const float* x   = (const float*)d_in[0];
    const int*   ei  = (const int*)d_in[1];
    const float* tmp = (const float*)d_in[2];
    const float* Wg  = (const float*)d_in[3];
    const float* bg  = (const float*)d_in[4];
    const float* W1  = (const float*)d_in[5];
    const float* b1  = (const float*)d_in[6];
    const float* W2  = (const float*)d_in[7];
    const float* b2  = (const float*)d_in[8];
    float* out = (float*)d_out;

    char* base = (char*)d_ws;
    int* off  = (int*)base;                                   // NN+1 ints (256KB slot)
    int* bcur = (int*)(base + (256 << 10));                   // 196 ints
    unsigned short* csr = (unsigned short*)(base + (512 << 10));       // NE ushort = 1.6MB
    unsigned short* Wt  = (unsigned short*)(base + ((size_t)3 << 20)); // NF*HH bf16
    unsigned short* Wt1 = Wt + NF * HH;                       // HH*ZK bf16
    unsigned short* hp_c = (unsigned short*)(base + ((size_t)4 << 20));  // 4*NN*CWP bf16 = 12.8MB
    float* xw2 = (float*)(base + ((size_t)17 << 20));         // NPAD floats
    int* temp  = (int*)(base + ((size_t)18 << 20));           // 196*CAP ints = 4.01MB

    k_init <<<1, 256, 0, stream>>>(bcur);
    k_pre  <<<FILLA_B + WBLK + W1BLK, 256, 0, stream>>>(ei, bcur, temp, Wg, W1, Wt, Wt1);
    k_gg   <<<NBK + GEMM_JOBS, 256, 0, stream>>>(temp, bcur, csr, off, x, Wt, W2, hp_c, xw2);
    k_am   <<<GEMM_JOBS, 256, 0, stream>>>(hp_c, off, csr, bg, tmp, Wt1, b1, W2, b2, xw2, out);
}

// Round 7
// 169.341 us; speedup vs baseline: 1.1116x; 1.1116x over previous
//
#include <hip/hip_runtime.h>
#include <hip/hip_bf16.h>

#define NN 50000
#define NPAD 50048           // 64-row padded for MFMA grid
#define NE 800000
#define NF 128
#define HH 96
#define TF 10
#define Z1DIM (HH + TF)   // 106
#define ZK 128            // padded K for layer-1 MFMA (Wt1 row stride)
#define NCH 4             // column chunks for the gather
#define CW 24             // real cols per chunk: NCH*CW == HH
#define CWP 32            // padded row stride (64B cache line); cols 28-29 hold fp32 dinv
#define NBK 196           // dst buckets of 256 nodes
#define CAP 5120          // per-bucket temp capacity
#define EPB 2048          // edges per fillA job (391 blocks)
#define FILLA_B ((NE + EPB - 1) / EPB)   // 391

#define WBLK (NF * HH / 4 / 256)       // 12
#define W1BLK (HH * ZK / 4 / 256)      // 12
#define ZPAD_JOBS 3                    // zero zb pad rows [NN,NPAD) all 128 cols
#define GEMM_JOBS (NPAD / 64)          // 782
#define AGG_JOBS (8 * 782)             // 6256

typedef __attribute__((ext_vector_type(8))) short short8;
typedef __attribute__((ext_vector_type(8))) unsigned short ushort8;
typedef __attribute__((ext_vector_type(4))) float f32x4;

__device__ __forceinline__ float bu2f(unsigned short u) {
    union { unsigned int i; float f; } c;
    c.i = ((unsigned int)u) << 16;
    return c.f;
}
__device__ __forceinline__ unsigned short f2bu(float f) {
    union { __hip_bfloat16 h; unsigned short u; } c;
    c.h = __float2bfloat16(f);
    return c.u;
}
__device__ __forceinline__ float u2f32(unsigned short lo, unsigned short hi) {
    union { unsigned int i; float f; } c;
    c.i = ((unsigned int)hi << 16) | lo;
    return c.f;
}

// ---- kernel 1: bcur[b] = b*CAP; off[NN] = NE ----
__global__ void k_init(int* __restrict__ bcur, int* __restrict__ off) {
    int t = threadIdx.x;
    if (t < NBK) bcur[t] = t * CAP;
    if (t == 255) off[NN] = NE;
}

// ---- kernel 2: fused {edge binning} | {weight transpose} | {zb pad rows} ----
__global__ __launch_bounds__(256) void k_pre(const int* __restrict__ ei,
                                             int* __restrict__ bcur,
                                             int* __restrict__ temp,
                                             const float* __restrict__ W,
                                             const float* __restrict__ W1,
                                             unsigned short* __restrict__ Wt,
                                             unsigned short* __restrict__ Wt1,
                                             unsigned short* __restrict__ zb) {
    const int t = threadIdx.x;
    if (blockIdx.x < FILLA_B) {
        // ---- fillA: bin edges into 196 dst-range buckets ----
        __shared__ int hist[NBK], bas[NBK];
        for (int m = t; m < NBK; m += 256) hist[m] = 0;
        __syncthreads();
        const int e0 = blockIdx.x * EPB;
        const int ecap = min(e0 + EPB, NE);
        for (int e = e0 + t; e < ecap; e += 256) {
            int d = ei[NE + e];
            atomicAdd(&hist[d >> 8], 1);
        }
        __syncthreads();
        for (int m = t; m < NBK; m += 256) {
            int c = hist[m];
            bas[m] = c ? atomicAdd(&bcur[m], c) : 0;
            hist[m] = 0;   // reuse as run cursor
        }
        __syncthreads();
        for (int e = e0 + t; e < ecap; e += 256) {
            int d = ei[NE + e], s = ei[e];
            int b = d >> 8;
            int r = atomicAdd(&hist[b], 1);
            temp[bas[b] + r] = ((d & 255) << 16) | s;
        }
        return;
    }
    int b = blockIdx.x - FILLA_B;
    if (b < WBLK) {
        int e = (b * 256 + t) * 4;
        int n = e >> 7, k = e & 127;
        ushort4 v;
        v.x = f2bu(W[(k + 0) * HH + n]);
        v.y = f2bu(W[(k + 1) * HH + n]);
        v.z = f2bu(W[(k + 2) * HH + n]);
        v.w = f2bu(W[(k + 3) * HH + n]);
        *(ushort4*)(Wt + e) = v;
    } else if (b < WBLK + W1BLK) {
        int e = ((b - WBLK) * 256 + t) * 4;
        int n = e >> 7, k = e & 127;     // n in [0,96), k in [0,128)
        ushort4 v;
        v.x = (k + 0 < Z1DIM) ? f2bu(W1[(k + 0) * HH + n]) : (unsigned short)0;
        v.y = (k + 1 < Z1DIM) ? f2bu(W1[(k + 1) * HH + n]) : (unsigned short)0;
        v.z = (k + 2 < Z1DIM) ? f2bu(W1[(k + 2) * HH + n]) : (unsigned short)0;
        v.w = (k + 3 < Z1DIM) ? f2bu(W1[(k + 3) * HH + n]) : (unsigned short)0;
        *(ushort4*)(Wt1 + e) = v;
    } else {
        // zero zb pad rows [NN,NPAD), all 128 cols: 6144 ushorts
        int e8 = ((b - WBLK - W1BLK) * 256 + t) * 8;
        ushort8 z = {};
        *(ushort8*)(zb + (size_t)NN * ZK + e8) = z;
    }
}

// ---- kernel 3: fused {fillB: off + dinv-in-pad + csr scatter} | {MFMA GEMM} ----
// fillB blocks [0,196): per-bucket histogram + scans -> off[i]; fp32 rsqrt(deg+1)
// into hp_c pad cols 28-29 of all 4 chunks; scatter csr.
// GEMM blocks [196,978): h = bf16(x)·Wt UNSCALED + fused x·W2[96:224] row-dot.
// MFMA operands SWAPPED (Wt frag first): D-rows = output cols n, D-cols = nodes
// -> each thread holds 4 consecutive n of one node -> ushort4 coalesced stores.
__global__ __launch_bounds__(256) void k_gg(const int* __restrict__ temp,
                                            const int* __restrict__ bcur,
                                            unsigned short* __restrict__ csr,
                                            int* __restrict__ off,
                                            const float* __restrict__ x,
                                            const unsigned short* __restrict__ Wt,
                                            const float* __restrict__ W2,
                                            unsigned short* __restrict__ hp_c,
                                            float* __restrict__ xw2) {
    const int t = threadIdx.x;
    if (blockIdx.x < NBK) {
        __shared__ int ls[256], lc[256];
        const int b = blockIdx.x;
        // exclusive scan of all bucket sizes -> this bucket's global base g0
        int szt = (t < NBK) ? (bcur[t] - t * CAP) : 0;
        ls[t] = szt;
        __syncthreads();
#pragma unroll
        for (int d = 1; d < 256; d <<= 1) {
            int u = (t >= d) ? ls[t - d] : 0;
            __syncthreads();
            ls[t] += u;
            __syncthreads();
        }
        const int g0 = (b > 0) ? ls[b - 1] : 0;
        __syncthreads();
        ls[t] = 0;
        __syncthreads();
        const int seg0 = b * CAP;
        const int m = bcur[b] - seg0;
        for (int k = t; k < m; k += 256) atomicAdd(&ls[temp[seg0 + k] >> 16], 1);
        __syncthreads();
        const int myc = ls[t];
        lc[t] = myc;
        __syncthreads();
#pragma unroll
        for (int d = 1; d < 256; d <<= 1) {
            int u = (t >= d) ? lc[t - d] : 0;
            __syncthreads();
            lc[t] += u;
            __syncthreads();
        }
        const int myoff = g0 + lc[t] - myc;   // absolute exclusive
        __syncthreads();
        lc[t] = myoff;                        // absolute cursor
        const int i = b * 256 + t;
        if (i < NN) {
            off[i] = myoff;
            const float dinv = rsqrtf((float)myc + 1.f);
#pragma unroll
            for (int cc = 0; cc < NCH; ++cc)
                *(float*)(hp_c + (size_t)cc * NN * CWP + (size_t)i * CWP + 28) = dinv;
        } else if (i == NN) {
            off[NN] = NE;
        }
        __syncthreads();
        for (int k = t; k < m; k += 256) {
            int v = temp[seg0 + k];
            int r = atomicAdd(&lc[v >> 16], 1);
            csr[r] = (unsigned short)(v & 0xFFFF);
        }
        return;
    }
    // ---- gemm (operand-swapped) ----
    const int wave = t >> 6;
    const int lane = t & 63;
    const int quad = lane >> 4;
    const int l16 = lane & 15;
    const int Mbase = (blockIdx.x - NBK) * 64 + wave * 16;
    const int node = Mbase + l16;
    const bool valid = node < NN;

    const float* xr = x + (size_t)node * NF + quad * 8;
    const unsigned short* brow = Wt + (size_t)l16 * NF + quad * 8;

    f32x4 acc[6] = {};
    float xs = 0.f;
#pragma unroll
    for (int ks = 0; ks < 4; ++ks) {
        short8 a = {};
        if (valid) {
            float4 f0 = *(const float4*)(xr + ks * 32);
            float4 f1 = *(const float4*)(xr + ks * 32 + 4);
            const float4 w0 = *(const float4*)(W2 + HH + quad * 8 + ks * 32);
            const float4 w1 = *(const float4*)(W2 + HH + quad * 8 + ks * 32 + 4);
            xs = fmaf(f0.x, w0.x, xs); xs = fmaf(f0.y, w0.y, xs);
            xs = fmaf(f0.z, w0.z, xs); xs = fmaf(f0.w, w0.w, xs);
            xs = fmaf(f1.x, w1.x, xs); xs = fmaf(f1.y, w1.y, xs);
            xs = fmaf(f1.z, w1.z, xs); xs = fmaf(f1.w, w1.w, xs);
            a[0] = (short)f2bu(f0.x); a[1] = (short)f2bu(f0.y);
            a[2] = (short)f2bu(f0.z); a[3] = (short)f2bu(f0.w);
            a[4] = (short)f2bu(f1.x); a[5] = (short)f2bu(f1.y);
            a[6] = (short)f2bu(f1.z); a[7] = (short)f2bu(f1.w);
        }
#pragma unroll
        for (int nt = 0; nt < 6; ++nt) {
            short8 bfrag = *(const short8*)(brow + (size_t)nt * 16 * NF + ks * 32);
            acc[nt] = __builtin_amdgcn_mfma_f32_16x16x32_bf16(bfrag, a, acc[nt], 0, 0, 0);
        }
    }
    xs += __shfl_xor(xs, 16, 64);
    xs += __shfl_xor(xs, 32, 64);
    if (quad == 0 && valid) xw2[node] = xs;

    if (valid) {
#pragma unroll
        for (int nt = 0; nt < 6; ++nt) {
            const int n0 = nt * 16 + quad * 4;       // 4 consecutive n, never crossing a chunk
            const int c = n0 / CW, jj = n0 - c * CW;
            ushort4 v;
            v.x = f2bu(acc[nt][0]); v.y = f2bu(acc[nt][1]);
            v.z = f2bu(acc[nt][2]); v.w = f2bu(acc[nt][3]);
            *(ushort4*)(hp_c + (size_t)c * NN * CWP + (size_t)node * CWP + jj) = v;
        }
    }
}

// ---- kernel 4: chunked gather-aggregate -> zb, XCD-affine ----
// 4 adjacent lanes (q) cooperatively load one 64B hp_c row per edge; q3's quarter
// carries fp32 dinv[src] in cols 28-29 -> reconstruct + __shfl(lane|3) broadcast.
// csr indices quad-batched: lane q loads csr[k+q] (one 8B segment per 4 edges),
// distributed via __shfl within the quad. 2 halves (h) split the edge list;
// combine shfl_xor(4). (c==3,q==3,h==0) lane writes the zb temporal tail.
__global__ __launch_bounds__(256) void k_agg(const unsigned short* __restrict__ hp_c,
                                             const int* __restrict__ off,
                                             const unsigned short* __restrict__ csr,
                                             const float* __restrict__ bg,
                                             const float* __restrict__ tmp,
                                             unsigned short* __restrict__ zb) {
    const int b = blockIdx.x;
    const int slot = b & 7;
    const int c = slot >> 1;                       // chunk: pinned to XCD pair
    const int r = (b >> 3) * 2 + (slot & 1);
    const int item = r * 256 + threadIdx.x;
    if (item >= NN * 8) return;
    const int i = item >> 3;
    const int sub = item & 7;
    const int q = sub & 3;                         // 16B quarter of the 64B row
    const int h = sub >> 2;                        // edge-range half
    const int lane = threadIdx.x & 63;
    const int qb = lane & 60;                      // quad base lane
    const int srcl = lane | 3;                     // q3 lane of this (i,h) quad
    const unsigned short* __restrict__ base = hp_c + (size_t)c * NN * CWP + q * 8;

    float a[8];
    if (h == 0) {  // self-loop term: dinv[i]*h[i]
        ushort8 sv = *(const ushort8*)(base + (size_t)i * CWP);
        float dsl = __shfl(u2f32(sv[4], sv[5]), srcl, 64);
#pragma unroll
        for (int j = 0; j < 8; ++j) a[j] = dsl * bu2f(sv[j]);
    } else {
#pragma unroll
        for (int j = 0; j < 8; ++j) a[j] = 0.f;
    }

    const int start = off[i];
    const int end = off[i + 1];
    const int len = end - start;
    const float dv = rsqrtf((float)len + 1.f);
    const int half0 = (len + 1) >> 1;
    int k = h ? start + half0 : start;
    const int ke = h ? end : start + half0;
    for (; k + 3 < ke; k += 4) {   // 4 edges x 1 line each in flight
        int myS = csr[k + q];      // quad loads one contiguous 8B segment
        int s0 = __shfl(myS, qb + 0, 64);
        int s1 = __shfl(myS, qb + 1, 64);
        int s2 = __shfl(myS, qb + 2, 64);
        int s3 = __shfl(myS, qb + 3, 64);
        ushort8 v0 = *(const ushort8*)(base + (size_t)s0 * CWP);
        ushort8 v1 = *(const ushort8*)(base + (size_t)s1 * CWP);
        ushort8 v2 = *(const ushort8*)(base + (size_t)s2 * CWP);
        ushort8 v3 = *(const ushort8*)(base + (size_t)s3 * CWP);
        float d0 = __shfl(u2f32(v0[4], v0[5]), srcl, 64);
        float d1 = __shfl(u2f32(v1[4], v1[5]), srcl, 64);
        float d2 = __shfl(u2f32(v2[4], v2[5]), srcl, 64);
        float d3 = __shfl(u2f32(v3[4], v3[5]), srcl, 64);
#pragma unroll
        for (int j = 0; j < 8; ++j) {
            float p0 = fmaf(d0, bu2f(v0[j]), a[j]);
            float p1 = fmaf(d2, bu2f(v2[j]), fmaf(d1, bu2f(v1[j]), 0.f));
            a[j] = fmaf(d3, bu2f(v3[j]), p0 + p1);
        }
    }
    for (; k < ke; ++k) {
        ushort8 v0 = *(const ushort8*)(base + (size_t)csr[k] * CWP);
        float d0 = __shfl(u2f32(v0[4], v0[5]), srcl, 64);
#pragma unroll
        for (int j = 0; j < 8; ++j) a[j] = fmaf(d0, bu2f(v0[j]), a[j]);
    }
#pragma unroll
    for (int j = 0; j < 8; ++j) a[j] += __shfl_xor(a[j], 4, 64);
    if (h == 0) {
        if (q < 3) {
            const int j0 = c * CW + q * 8;
            ushort8 o;
#pragma unroll
            for (int j = 0; j < 8; ++j)
                o[j] = f2bu(fmaxf(fmaf(dv, a[j], bg[j0 + j]), 0.f));
            *(ushort8*)(zb + (size_t)i * ZK + j0) = o;
        } else if (c == 3) {
            // zb temporal tail: cols [96,128) = bf16(tmp[i][0..10)) then zeros
            const float* tp = tmp + (size_t)i * TF;
            ushort8 o0, z = {};
#pragma unroll
            for (int j = 0; j < 8; ++j) o0[j] = f2bu(tp[j]);
            ushort8 o1 = z;
            o1[0] = f2bu(tp[8]);
            o1[1] = f2bu(tp[9]);
            unsigned short* zp = zb + (size_t)i * ZK + HH;
            *(ushort8*)(zp) = o0;
            *(ushort8*)(zp + 8) = o1;
            *(ushort8*)(zp + 16) = z;
            *(ushort8*)(zp + 24) = z;
        }
    }
}

// ---- kernel 5: MFMA layer-1 + fused layer-2 epilogue (operand-swapped) ----
// D-rows = hidden cols n (thread holds 24 of them for one node) -> layer-2
// reduce is 24 fma + 2 shfls; b1/W2 load as float4; out write coalesced.
__global__ __launch_bounds__(256) void k_mlp2(const unsigned short* __restrict__ zb,
                                              const unsigned short* __restrict__ Wt1,
                                              const float* __restrict__ b1,
                                              const float* __restrict__ W2,
                                              const float* __restrict__ b2,
                                              const float* __restrict__ xw2,
                                              float* __restrict__ out) {
    const int wave = threadIdx.x >> 6;
    const int lane = threadIdx.x & 63;
    const int quad = lane >> 4;
    const int l16 = lane & 15;
    const int Mbase = blockIdx.x * 64 + wave * 16;
    const int node = Mbase + l16;

    const unsigned short* arow = zb + (size_t)node * ZK + quad * 8;
    const unsigned short* brow = Wt1 + (size_t)l16 * ZK + quad * 8;

    f32x4 acc[6] = {};
#pragma unroll
    for (int ks = 0; ks < 4; ++ks) {
        short8 a = *(const short8*)(arow + ks * 32);
#pragma unroll
        for (int nt = 0; nt < 6; ++nt) {
            short8 bfrag = *(const short8*)(brow + (size_t)nt * 16 * ZK + ks * 32);
            acc[nt] = __builtin_amdgcn_mfma_f32_16x16x32_bf16(bfrag, a, acc[nt], 0, 0, 0);
        }
    }
    float p = 0.f;
#pragma unroll
    for (int nt = 0; nt < 6; ++nt) {
        const int n0 = nt * 16 + quad * 4;
        const float4 bb = *(const float4*)(b1 + n0);
        const float4 ww = *(const float4*)(W2 + n0);
        p = fmaf(fmaxf(acc[nt][0] + bb.x, 0.f), ww.x, p);
        p = fmaf(fmaxf(acc[nt][1] + bb.y, 0.f), ww.y, p);
        p = fmaf(fmaxf(acc[nt][2] + bb.z, 0.f), ww.z, p);
        p = fmaf(fmaxf(acc[nt][3] + bb.w, 0.f), ww.w, p);
    }
    p += __shfl_xor(p, 16, 64);
    p += __shfl_xor(p, 32, 64);
    if (quad == 0 && node < NN)
        out[node] = fmaxf(p + xw2[node] + b2[0], 0.f);
}

extern "C" void kernel_launch(void* const* d_in, const int* in_sizes, int n_in,
                              void* d_out, int out_size, void* d_ws, size_t ws_size,
                              hipStream_t stream) {
    const float* x   = (const float*)d_in[0];
    const int*   ei  = (const int*)d_in[1];
    const float* tmp = (const float*)d_in[2];
    const float* Wg  = (const float*)d_in[3];
    const float* bg  = (const float*)d_in[4];
    const float* W1  = (const float*)d_in[5];
    const float* b1  = (const float*)d_in[6];
    const float* W2  = (const float*)d_in[7];
    const float* b2  = (const float*)d_in[8];
    float* out = (float*)d_out;

    char* base = (char*)d_ws;
    int* off  = (int*)base;                                   // NN+1 ints (256KB slot)
    int* bcur = (int*)(base + (256 << 10));                   // 196 ints
    unsigned short* csr = (unsigned short*)(base + (512 << 10));       // NE ushort = 1.6MB
    unsigned short* Wt  = (unsigned short*)(base + ((size_t)3 << 20)); // NF*HH bf16
    unsigned short* Wt1 = Wt + NF * HH;                       // HH*ZK bf16
    unsigned short* hp_c = (unsigned short*)(base + ((size_t)4 << 20));  // 4*NN*CWP bf16 = 12.8MB
    unsigned short* zb  = (unsigned short*)(base + ((size_t)17 << 20));  // NPAD*ZK bf16 = 12.8MB
    float* xw2 = (float*)(base + ((size_t)30 << 20));         // NPAD floats
    int* temp  = (int*)(base + ((size_t)31 << 20));           // 196*CAP ints = 4.01MB

    k_init <<<1, 256, 0, stream>>>(bcur, off);
    k_pre  <<<FILLA_B + WBLK + W1BLK + ZPAD_JOBS, 256, 0, stream>>>(
                ei, bcur, temp, Wg, W1, Wt, Wt1, zb);
    k_gg   <<<NBK + GEMM_JOBS, 256, 0, stream>>>(temp, bcur, csr, off, x, Wt, W2, hp_c, xw2);
    k_agg  <<<AGG_JOBS, 256, 0, stream>>>(hp_c, off, csr, bg, tmp, zb);
    k_mlp2 <<<GEMM_JOBS, 256, 0, stream>>>(zb, Wt1, b1, W2, b2, xw2, out);
}